// Round 1
// baseline (1305.807 us; speedup 1.0000x reference)
//
#include <hip/hip_runtime.h>

// Shapes fixed by reference setup_inputs():
//   x: (8, 128, 512, 512) fp32, W: (1,128,1,1), b: (1,), out: (8,1,512,512)
static constexpr int       C_      = 128;
static constexpr long long HW_     = 512LL * 512LL;   // 262144 pixels per plane
static constexpr long long HW4_    = HW_ / 4;         // 65536 float4 per plane
static constexpr int       LOG_HW4 = 16;              // log2(HW4_)
static constexpr float     QMAX    = 127.0f;          // 2^(8-1)-1

static constexpr int BLK  = 256;                      // threads per block
static constexpr int PIX  = 4;                        // float4 outputs per thread
static constexpr int TILE = BLK * PIX;                // 1024 float4 per block (16 KiB/channel)

// --- Kernel 1: quant-dequant the 128 weights into d_ws -----------------------
// scale = max|W|/127; Wq = clip(rint(W/scale), -127, 127) * scale
// rintf = round-half-to-even, matching jnp.round.
__global__ void quant_w_kernel(const float* __restrict__ W,
                               float* __restrict__ Wq) {
    __shared__ float red[C_];
    int i = threadIdx.x;
    float v = W[i];
    red[i] = fabsf(v);
    __syncthreads();
    #pragma unroll
    for (int s = C_ / 2; s > 0; s >>= 1) {
        if (i < s) red[i] = fmaxf(red[i], red[i + s]);
        __syncthreads();
    }
    float scale = red[0] / QMAX;
    float q = rintf(v / scale);
    q = fminf(fmaxf(q, -QMAX), QMAX);
    Wq[i] = q * scale;
}

// --- Kernel 2: streaming channel reduction, pixel-register-blocked -----------
// Each thread produces PIX=4 float4 outputs, wave-strided by BLK so every load
// instruction stays perfectly coalesced (64 lanes x 16 B = 1 KiB contiguous).
// Per channel-pair the thread issues 8 independent loads whose cache lines
// spread across 32 L2 sets (4 KiB pixel footprint) with only 2 lines per set —
// vs the old layout's 16 in-flight lines all aliasing ONE set (1 MiB channel
// stride keeps L2 set bits [17:7] invariant), which throttled miss issue.
__global__ __launch_bounds__(BLK) void conv1x1_kernel(
    const float4* __restrict__ x, const float* __restrict__ Wq,
    const float* __restrict__ bias, float4* __restrict__ out) {
    __shared__ float w[C_];
    if (threadIdx.x < C_) w[threadIdx.x] = Wq[threadIdx.x];
    __syncthreads();

    long long base4 = (long long)blockIdx.x * TILE;   // first float4 of this tile
    long long b     = base4 >> LOG_HW4;               // batch index (TILE divides HW4_)
    long long p4    = (base4 & (HW4_ - 1)) + threadIdx.x;
    const float4* xp = x + (b * C_) * HW4_ + p4;

    float4 acc0[PIX], acc1[PIX];
    #pragma unroll
    for (int p = 0; p < PIX; ++p) {
        acc0[p] = {0.f, 0.f, 0.f, 0.f};
        acc1[p] = {0.f, 0.f, 0.f, 0.f};
    }

    for (int c = 0; c < C_; c += 2) {
        const float4* x0 = xp + (long long)c * HW4_;
        const float4* x1 = x0 + HW4_;
        float4 v0[PIX], v1[PIX];
        #pragma unroll
        for (int p = 0; p < PIX; ++p) v0[p] = x0[p * BLK];
        #pragma unroll
        for (int p = 0; p < PIX; ++p) v1[p] = x1[p * BLK];
        float w0 = w[c], w1 = w[c + 1];
        #pragma unroll
        for (int p = 0; p < PIX; ++p) {
            acc0[p].x += v0[p].x * w0; acc0[p].y += v0[p].y * w0;
            acc0[p].z += v0[p].z * w0; acc0[p].w += v0[p].w * w0;
            acc1[p].x += v1[p].x * w1; acc1[p].y += v1[p].y * w1;
            acc1[p].z += v1[p].z * w1; acc1[p].w += v1[p].w * w1;
        }
    }

    float bb = bias[0];
    float4* op = out + base4 + threadIdx.x;
    #pragma unroll
    for (int p = 0; p < PIX; ++p) {
        float4 r;
        r.x = acc0[p].x + acc1[p].x + bb;
        r.y = acc0[p].y + acc1[p].y + bb;
        r.z = acc0[p].z + acc1[p].z + bb;
        r.w = acc0[p].w + acc1[p].w + bb;
        op[p * BLK] = r;
    }
}

extern "C" void kernel_launch(void* const* d_in, const int* in_sizes, int n_in,
                              void* d_out, int out_size, void* d_ws, size_t ws_size,
                              hipStream_t stream) {
    const float* x    = (const float*)d_in[0];
    const float* W    = (const float*)d_in[1];
    const float* bias = (const float*)d_in[2];
    float* out = (float*)d_out;
    float* Wq  = (float*)d_ws;   // 128 floats of scratch (re-poisoned every call,
                                 // so quant_w_kernel must run every call — it does)

    quant_w_kernel<<<1, C_, 0, stream>>>(W, Wq);

    long long n4   = (long long)out_size / 4;            // 524288 float4 outputs
    int       grid = (int)((n4 + TILE - 1) / TILE);      // 512 blocks
    conv1x1_kernel<<<grid, BLK, 0, stream>>>((const float4*)x, Wq, bias,
                                             (float4*)out);
}